// Round 2
// baseline (58024.188 us; speedup 1.0000x reference)
//
#include <hip/hip_runtime.h>
#include <math.h>

// Problem constants
#define BB 32
#define CC 512
#define SS 256      // kv tokens
#define DD 2048     // d_model
#define DIN 512
#define NH 8
#define DHD 64
#define TT 50
#define MM 25
#define HHID 16
#define NSA 512
#define NSO 512
#define NOUT 1000

#define NBLK 256    // persistent grid size (== CU count; must all be resident)

// ---------------------------------------------------------------------------
// Init: barrier counter, decays, sync states (buffer 0 of ping-pong), act0,
// trace0
// ---------------------------------------------------------------------------
__global__ void init_kernel(const float* __restrict__ dec_a, const float* __restrict__ dec_o,
                            const float* __restrict__ start_act, const float* __restrict__ start_trace,
                            const int* __restrict__ idx_lo, const int* __restrict__ idx_ro,
                            unsigned* __restrict__ bar,
                            float* __restrict__ r_a, float* __restrict__ r_o,
                            float* __restrict__ a_a, float* __restrict__ b_a,
                            float* __restrict__ a_o, float* __restrict__ b_o,
                            float* __restrict__ act, float* __restrict__ trace)
{
    int i = blockIdx.x * 256 + threadIdx.x;
    if (i < 16) bar[i] = 0u;
    if (i < 512) {
        r_a[i] = expf(-fminf(fmaxf(dec_a[i], 0.f), 15.f));
        r_o[i] = expf(-fminf(fmaxf(dec_o[i], 0.f), 15.f));
    }
    if (i < BB * NSA) {
        a_a[i] = 0.f; b_a[i] = 0.f;
        int j = i & 511;
        a_o[i] = start_act[idx_lo[j]] * start_act[idx_ro[j]];
        b_o[i] = 1.f;
    }
    if (i < BB * DD) act[i] = start_act[i & (DD - 1)];
    if (i < BB * MM * DD) {
        int rem = i % (MM * DD);
        int m = rem / DD, d = rem % DD;
        trace[i] = start_trace[d * MM + m];   // start_trace is (D,M)
    }
}

// ---------------------------------------------------------------------------
// Generic 64x64 tiled GEMM (precompute only). AMODE 0: row-major A[row*K+k].
// AMODE 1: A is x (B,C,S) with row=(b,s), k=c. SMODE 0: plain row-major +
// bias. SMODE 1: store khT (B,H,DH,S). SMODE 2: store vh (B,H,S,DH).
// ---------------------------------------------------------------------------
template<int AMODE, int SMODE>
__global__ void gemm64(const float* __restrict__ A, const float* __restrict__ Bm,
                       const float* __restrict__ bias, float* __restrict__ Cm,
                       int Mdim, int Ndim, int Kdim)
{
    __shared__ float As[16 * 65];
    __shared__ float Bs[16 * 64];
    int row0 = blockIdx.x * 64;
    int col0 = blockIdx.y * 64;
    int t = threadIdx.x;
    int tx = t & 15, ty = t >> 4;
    float acc[4][4] = {};
    for (int k0 = 0; k0 < Kdim; k0 += 16) {
        if (AMODE == 0) {
            for (int i = t; i < 1024; i += 256) {
                int kk = i & 15, r = i >> 4;
                As[kk * 65 + r] = A[(size_t)(row0 + r) * Kdim + k0 + kk];
            }
        } else {
            int b = row0 / SS, s0 = row0 % SS;
            for (int i = t; i < 1024; i += 256) {
                int r = i & 63, kk = i >> 6;
                As[kk * 65 + r] = A[((size_t)b * CC + k0 + kk) * SS + s0 + r];
            }
        }
        for (int i = t; i < 1024; i += 256) {
            int c = i & 63, kk = i >> 6;
            Bs[kk * 64 + c] = Bm[(size_t)(k0 + kk) * Ndim + col0 + c];
        }
        __syncthreads();
        #pragma unroll
        for (int kk = 0; kk < 16; ++kk) {
            float a[4], bb[4];
            #pragma unroll
            for (int i = 0; i < 4; i++) a[i] = As[kk * 65 + ty * 4 + i];
            #pragma unroll
            for (int j = 0; j < 4; j++) bb[j] = Bs[kk * 64 + tx * 4 + j];
            #pragma unroll
            for (int i = 0; i < 4; i++)
                #pragma unroll
                for (int j = 0; j < 4; j++) acc[i][j] += a[i] * bb[j];
        }
        __syncthreads();
    }
    #pragma unroll
    for (int i = 0; i < 4; i++)
        #pragma unroll
        for (int j = 0; j < 4; j++) {
            int row = row0 + ty * 4 + i, col = col0 + tx * 4 + j;
            float v = acc[i][j] + (bias ? bias[col] : 0.f);
            if (SMODE == 0) {
                Cm[(size_t)row * Ndim + col] = v;
            } else if (SMODE == 1) {
                int b = row / SS, s = row % SS, h = col >> 6, dh = col & 63;
                Cm[(((size_t)b * NH + h) * DHD + dh) * SS + s] = v;
            } else {
                int b = row / SS, s = row % SS, h = col >> 6, dh = col & 63;
                Cm[(((size_t)b * NH + h) * SS + s) * DHD + dh] = v;
            }
        }
}

// LayerNorm over rows of 512 (in place), g/b applied
__global__ void ln_rows(float* __restrict__ buf, const float* __restrict__ g,
                        const float* __restrict__ bta)
{
    int row = blockIdx.x, t = threadIdx.x;
    __shared__ float red[256];
    float v0 = buf[(size_t)row * 512 + t];
    float v1 = buf[(size_t)row * 512 + 256 + t];
    red[t] = v0 + v1; __syncthreads();
    for (int off = 128; off; off >>= 1) { if (t < off) red[t] += red[t + off]; __syncthreads(); }
    float mu = red[0] * (1.f / 512.f); __syncthreads();
    float d0 = v0 - mu, d1 = v1 - mu;
    red[t] = d0 * d0 + d1 * d1; __syncthreads();
    for (int off = 128; off; off >>= 1) { if (t < off) red[t] += red[t + off]; __syncthreads(); }
    float rstd = 1.f / sqrtf(red[0] * (1.f / 512.f) + 1e-5f);
    buf[(size_t)row * 512 + t]       = d0 * rstd * g[t] + bta[t];
    buf[(size_t)row * 512 + 256 + t] = d1 * rstd * g[t + 256] + bta[t + 256];
}

// bqq = q_b @ Wq + bq
__global__ void bqq_kernel(const float* __restrict__ q_b, const float* __restrict__ Wq,
                           const float* __restrict__ bq, float* __restrict__ bqq)
{
    int c = blockIdx.x * 256 + threadIdx.x;
    if (c >= 512) return;
    float acc = bq[c];
    for (int k = 0; k < 512; k++) acc += q_b[k] * Wq[k * 512 + c];
    bqq[c] = acc;
}

// bias2 = bo @ syn_w[0:512,:] + syn_b
__global__ void bias2_kernel(const float* __restrict__ bo, const float* __restrict__ syn_w,
                             const float* __restrict__ syn_b, float* __restrict__ bias2)
{
    int c = blockIdx.x * 256 + threadIdx.x;
    if (c >= 4096) return;
    float acc = syn_b[c];
    for (int k = 0; k < 512; k++) acc += bo[k] * syn_w[(size_t)k * 4096 + c];
    bias2[c] = acc;
}

// ---------------------------------------------------------------------------
// Hand-rolled grid barrier (graph-capture safe, unlike cooperative launch).
// Single monotone arrival counter: barrier k complete when ctr >= NBLK*k.
// No reset, no generation -> no ABA race. Arrival is a release RMW at agent
// scope; the poll is a coherent (non-RMW) agent-scope load, so it cannot
// spin on a stale per-XCD L2 line.
// ---------------------------------------------------------------------------
__device__ __forceinline__ void gsync(unsigned* __restrict__ ctr, unsigned target)
{
    __syncthreads();
    if (threadIdx.x == 0) {
        __threadfence();
        __hip_atomic_fetch_add(ctr, 1u, __ATOMIC_RELEASE, __HIP_MEMORY_SCOPE_AGENT);
        while (__hip_atomic_load(ctr, __ATOMIC_ACQUIRE, __HIP_MEMORY_SCOPE_AGENT) < target)
            __builtin_amdgcn_s_sleep(2);
        __threadfence();
    }
    __syncthreads();
}

// ---------------------------------------------------------------------------
// Persistent tick kernel: the whole T=50 recurrence, 5 grid barriers/tick.
// Grid MUST be NBLK=256 blocks x 256 threads (>=1 block/CU -> all resident).
// ---------------------------------------------------------------------------
struct TickArgs {
    const float* Wqq; const float* bqq;
    const float* khT; const float* vh;
    const float* W2;  const float* syn_w; const float* bias2;
    const float* g_syn; const float* bt_syn;
    const float* w1; const float* b1; const float* w2; const float* b2;
    const float* out_w; const float* out_b;
    const float* r_a; const float* r_o;
    const int* la; const int* ra; const int* lo; const int* ro;
    float* a_a; float* b_a;      // [2][BB*512] ping-pong
    float* a_o; float* b_o;      // [2][BB*512] ping-pong
    float* act; float* trace; float* obuf; float* upart; float* ppart;
    float* out; float* out_sync;
    unsigned* bar;
};

__device__ __forceinline__ void block_cert(const float* __restrict__ ppart,
                                           const float* __restrict__ out_b,
                                           float* __restrict__ d_out, int b, int t_iter,
                                           float* red)
{
    int t = threadIdx.x;
    float pv[4];
    float mx = -1e30f;
    #pragma unroll
    for (int ii = 0; ii < 4; ++ii) {
        int c = t + ii * 256;
        float v = -1e30f;
        if (c < 1000) {
            v = out_b[c];
            for (int ks = 0; ks < 8; ++ks) v += ppart[(size_t)(ks * 32 + b) * 1000 + c];
            d_out[(size_t)b * NOUT * TT + (size_t)c * TT + t_iter] = v;
        }
        pv[ii] = v;
        mx = fmaxf(mx, v);
    }
    red[t] = mx; __syncthreads();
    for (int off = 128; off; off >>= 1) { if (t < off) red[t] = fmaxf(red[t], red[t + off]); __syncthreads(); }
    mx = red[0]; __syncthreads();
    float s1 = 0.f, s2 = 0.f;
    #pragma unroll
    for (int ii = 0; ii < 4; ++ii) {
        int c = t + ii * 256;
        if (c < 1000) { float xx = pv[ii] - mx; float e = expf(xx); s1 += e; s2 += e * xx; }
    }
    red[t] = s1; __syncthreads();
    for (int off = 128; off; off >>= 1) { if (t < off) red[t] += red[t + off]; __syncthreads(); }
    s1 = red[0]; __syncthreads();
    red[t] = s2; __syncthreads();
    for (int off = 128; off; off >>= 1) { if (t < off) red[t] += red[t + off]; __syncthreads(); }
    s2 = red[0];
    if (t == 0) {
        float ne = -(s2 / s1 - logf(s1)) * (1.f / logf(1000.f));
        size_t base = (size_t)BB * NOUT * TT + (size_t)b * 2 * TT + t_iter;
        d_out[base] = ne;
        d_out[base + TT] = 1.f - ne;
    }
    __syncthreads();
}

__device__ __forceinline__ void block_glu_ln(const float* __restrict__ upart,
                                             const float* __restrict__ bias2,
                                             const float* __restrict__ g,
                                             const float* __restrict__ bta,
                                             float* __restrict__ trace, int t_iter, int b,
                                             float* red)
{
    int t = threadIdx.x;
    float vals[8];
    float loc = 0.f;
    #pragma unroll
    for (int ii = 0; ii < 8; ++ii) {
        int d = t + ii * 256;
        float a = bias2[d], bb = bias2[d + 2048];
        for (int ks = 0; ks < 16; ++ks) {
            const float* rowp = upart + (size_t)(ks * 32 + b) * 4096;
            a += rowp[d];
            bb += rowp[d + 2048];
        }
        float gl = a * (1.f / (1.f + expf(-bb)));
        vals[ii] = gl; loc += gl;
    }
    red[t] = loc; __syncthreads();
    for (int off = 128; off; off >>= 1) { if (t < off) red[t] += red[t + off]; __syncthreads(); }
    float mu = red[0] * (1.f / 2048.f); __syncthreads();
    float l2 = 0.f;
    #pragma unroll
    for (int ii = 0; ii < 8; ++ii) { float dq = vals[ii] - mu; l2 += dq * dq; }
    red[t] = l2; __syncthreads();
    for (int off = 128; off; off >>= 1) { if (t < off) red[t] += red[t + off]; __syncthreads(); }
    float rstd = 1.f / sqrtf(red[0] * (1.f / 2048.f) + 1e-5f);
    float* trow = trace + ((size_t)b * MM + (t_iter % MM)) * DD;
    #pragma unroll
    for (int ii = 0; ii < 8; ++ii) {
        int d = t + ii * 256;
        trow[d] = (vals[ii] - mu) * rstd * g[d] + bta[d];
    }
}

__global__ __launch_bounds__(256) void tick_kernel(TickArgs A)
{
    __shared__ float smem[32 * 161];   // 20.6 KB, unioned across phases
    const int blk = blockIdx.x;
    const int tid = threadIdx.x;
    unsigned nb = 0;                   // barrier target accumulator

    for (int t = 0; t < TT; ++t) {
        const int par = t & 1;

        // ============ P1: sync_a + qh slice + attention, block = (b,h) ======
        {
            int b = blk >> 3, h = blk & 7;
            float* sa  = smem;          // 512
            float* qp  = smem + 512;    // 256
            float* qs  = smem + 768;    // 64
            float* ps  = smem + 832;    // 256
            float* red = smem + 1088;   // 256
            const float* aold = A.a_a + par * (BB * 512);
            const float* bold = A.b_a + par * (BB * 512);
            float* anew = A.a_a + (par ^ 1) * (BB * 512);
            float* bnew = A.b_a + (par ^ 1) * (BB * 512);
            const float* actb = A.act + b * DD;
            for (int j = tid; j < 512; j += 256) {
                float p = actb[A.la[j]] * actb[A.ra[j]];
                float r = A.r_a[j];
                float aa = r * aold[b * 512 + j] + p;
                float bb = r * bold[b * 512 + j] + 1.f;
                sa[j] = aa / sqrtf(bb);
                if (h == 0) { anew[b * 512 + j] = aa; bnew[b * 512 + j] = bb; }
            }
            __syncthreads();
            // qh slice for this head: c = h*64 + cl, K split into 4 chunks
            {
                int cl = tid & 63, q = tid >> 6;
                const float* wcol = A.Wqq + h * 64 + cl;
                float acc = 0.f;
                #pragma unroll 8
                for (int k = q * 128; k < q * 128 + 128; ++k)
                    acc += sa[k] * wcol[k * 512];
                qp[tid] = acc;
            }
            __syncthreads();
            if (tid < 64)
                qs[tid] = qp[tid] + qp[tid + 64] + qp[tid + 128] + qp[tid + 192]
                        + A.bqq[h * 64 + tid];
            __syncthreads();
            // scores (thread = s)
            const float* kb = A.khT + (size_t)blk * 64 * 256;   // [dh][s]
            float sc = 0.f;
            #pragma unroll 8
            for (int dh = 0; dh < 64; ++dh) sc += qs[dh] * kb[dh * 256 + tid];
            sc *= 0.125f;
            red[tid] = sc; __syncthreads();
            for (int off = 128; off; off >>= 1) { if (tid < off) red[tid] = fmaxf(red[tid], red[tid + off]); __syncthreads(); }
            float mx = red[0]; __syncthreads();
            float e = expf(sc - mx);
            red[tid] = e; __syncthreads();
            for (int off = 128; off; off >>= 1) { if (tid < off) red[tid] += red[tid + off]; __syncthreads(); }
            float inv = 1.f / red[0];
            ps[tid] = e * inv;
            __syncthreads();
            int dh = tid & 63, ch = tid >> 6;
            const float* vb = A.vh + (size_t)blk * 256 * 64;    // [s][dh]
            float acc = 0.f;
            for (int s = ch * 64; s < ch * 64 + 64; ++s) acc += ps[s] * vb[s * 64 + dh];
            red[tid] = acc; __syncthreads();
            if (tid < 128) red[tid] += red[tid + 128];
            __syncthreads();
            if (tid < 64) A.obuf[b * 512 + h * 64 + tid] = red[tid] + red[tid + 64];
        }
        nb += NBLK; gsync(A.bar, nb);

        // ============ P2: synapse GEMM, 512 k-split units, 2 per block ======
        for (int rep = 0; rep < 2; ++rep) {
            int unit = blk * 2 + rep;
            int n0 = (unit & 31) * 128;
            int ks = unit >> 5;
            int k0 = ks * 160;
            float* As = smem;   // 32*161
            __syncthreads();
            for (int i = tid; i < 32 * 160; i += 256) {
                int k = i % 160, r = i / 160;
                int kk = k0 + k;
                float v = (kk < 512) ? A.obuf[r * 512 + kk] : A.act[r * 2048 + (kk - 512)];
                As[r * 161 + k] = v;
            }
            __syncthreads();
            int ct = tid & 31, rt = tid >> 5;
            int c0 = n0 + ct * 4;
            int rt4 = rt * 4;
            float acc[4][4] = {};
            #pragma unroll 2
            for (int k = 0; k < 160; ++k) {
                int kk = k0 + k;
                const float* wr = (kk < 512 ? A.W2 : A.syn_w) + (size_t)kk * 4096 + c0;
                float4 w4 = *(const float4*)wr;
                float a0 = As[(rt4 + 0) * 161 + k];
                float a1 = As[(rt4 + 1) * 161 + k];
                float a2 = As[(rt4 + 2) * 161 + k];
                float a3 = As[(rt4 + 3) * 161 + k];
                acc[0][0] += a0 * w4.x; acc[0][1] += a0 * w4.y; acc[0][2] += a0 * w4.z; acc[0][3] += a0 * w4.w;
                acc[1][0] += a1 * w4.x; acc[1][1] += a1 * w4.y; acc[1][2] += a1 * w4.z; acc[1][3] += a1 * w4.w;
                acc[2][0] += a2 * w4.x; acc[2][1] += a2 * w4.y; acc[2][2] += a2 * w4.z; acc[2][3] += a2 * w4.w;
                acc[3][0] += a3 * w4.x; acc[3][1] += a3 * w4.y; acc[3][2] += a3 * w4.z; acc[3][3] += a3 * w4.w;
            }
            #pragma unroll
            for (int i = 0; i < 4; i++) {
                float4 v = make_float4(acc[i][0], acc[i][1], acc[i][2], acc[i][3]);
                *(float4*)(A.upart + ((size_t)(ks * 32) + rt4 + i) * 4096 + c0) = v;
            }
        }
        nb += NBLK; gsync(A.bar, nb);

        // ============ P3: glu_ln (blk 0..31) ================================
        if (blk < 32) {
            block_glu_ln(A.upart, A.bias2, A.g_syn, A.bt_syn, A.trace, t, blk, smem);
        }
        nb += NBLK; gsync(A.bar, nb);

        // ============ P4: per-neuron MLP -> act =============================
        {
            int i = blk * 256 + tid;
            int b = i >> 11, d = i & 2047;
            float hp[32];
            #pragma unroll
            for (int h = 0; h < 32; h++) hp[h] = A.b1[d * 32 + h];
            const float* tr = A.trace + (size_t)b * MM * DD;
            for (int m = 0; m < 25; m++) {
                int mph = (t + 1 + m) % 25;     // logical->physical circular map
                float tv = tr[mph * DD + d];
                #pragma unroll
                for (int h = 0; h < 32; h++) hp[h] += tv * A.w1[((size_t)m * 32 + h) * DD + d];
            }
            float o0 = A.b2[d * 2], o1 = A.b2[d * 2 + 1];
            #pragma unroll
            for (int h = 0; h < 16; h++) {
                float hv = hp[h] * (1.f / (1.f + expf(-hp[h + 16])));
                o0 += hv * A.w2[((size_t)h * 2) * DD + d];
                o1 += hv * A.w2[((size_t)h * 2 + 1) * DD + d];
            }
            A.act[i] = o0 * (1.f / (1.f + expf(-o1)));
        }
        nb += NBLK; gsync(A.bar, nb);

        // ============ P5: sync_o fused into pred GEMM (blk 0..63) ===========
        if (blk < 64) {
            int ks = blk >> 3, ctile = blk & 7;
            int k0 = ks * 64;
            const float* aold = A.a_o + par * (BB * 512);
            const float* bold = A.b_o + par * (BB * 512);
            float* anew = A.a_o + (par ^ 1) * (BB * 512);
            float* bnew = A.b_o + (par ^ 1) * (BB * 512);
            float* As = smem;   // 32*65
            #pragma unroll
            for (int q = 0; q < 8; ++q) {
                int idx = tid + q * 256;          // 0..2047
                int r = idx >> 6, jl = idx & 63;
                int j = k0 + jl;
                const float* actb = A.act + r * DD;
                float p = actb[A.lo[j]] * actb[A.ro[j]];
                float rr = A.r_o[j];
                float aa = rr * aold[r * 512 + j] + p;
                float bb = rr * bold[r * 512 + j] + 1.f;
                float s = aa / sqrtf(bb);
                As[r * 65 + jl] = s;
                if (ctile == 0) {
                    anew[r * 512 + j] = aa;
                    bnew[r * 512 + j] = bb;
                    if (t == TT - 1) A.out_sync[r * 512 + j] = s;
                }
            }
            __syncthreads();
            int ct = tid & 31, rt = tid >> 5;
            int cc = ctile * 128 + ct * 4;
            int rt4 = rt * 4;
            if (cc < 1000) {
                float acc[4][4] = {};
                #pragma unroll 4
                for (int k = 0; k < 64; ++k) {
                    const float* wr = A.out_w + (size_t)(k0 + k) * 1000 + cc;
                    float w0 = wr[0], w1 = wr[1], w2 = wr[2], w3 = wr[3];
                    float a0 = As[(rt4 + 0) * 65 + k];
                    float a1 = As[(rt4 + 1) * 65 + k];
                    float a2 = As[(rt4 + 2) * 65 + k];
                    float a3 = As[(rt4 + 3) * 65 + k];
                    acc[0][0] += a0 * w0; acc[0][1] += a0 * w1; acc[0][2] += a0 * w2; acc[0][3] += a0 * w3;
                    acc[1][0] += a1 * w0; acc[1][1] += a1 * w1; acc[1][2] += a1 * w2; acc[1][3] += a1 * w3;
                    acc[2][0] += a2 * w0; acc[2][1] += a2 * w1; acc[2][2] += a2 * w2; acc[2][3] += a2 * w3;
                    acc[3][0] += a3 * w0; acc[3][1] += a3 * w1; acc[3][2] += a3 * w2; acc[3][3] += a3 * w3;
                }
                #pragma unroll
                for (int i = 0; i < 4; i++)
                    #pragma unroll
                    for (int j = 0; j < 4; j++)
                        A.ppart[(size_t)(ks * 32 + rt4 + i) * 1000 + cc + j] = acc[i][j];
            }
        }
        nb += NBLK; gsync(A.bar, nb);

        // ============ P6: cert for tick t (blk 224..255), no trailing sync ==
        // Overlaps next tick's P1. Its only input (ppart) is next written in
        // P5 of tick t+1, which is 4 barriers away -> race-free.
        if (blk >= 224) {
            block_cert(A.ppart, A.out_b, A.out, blk - 224, t, smem);
        }
    }
}

// ---------------------------------------------------------------------------
extern "C" void kernel_launch(void* const* d_in, const int* in_sizes, int n_in,
                              void* d_out, int out_size, void* d_ws, size_t ws_size,
                              hipStream_t stream)
{
    const float* x        = (const float*)d_in[0];
    const float* kv_w     = (const float*)d_in[1];
    const float* kv_b     = (const float*)d_in[2];
    const float* ln_kv_g  = (const float*)d_in[3];
    const float* ln_kv_b  = (const float*)d_in[4];
    const float* q_w      = (const float*)d_in[5];
    const float* q_b      = (const float*)d_in[6];
    const float* Wq       = (const float*)d_in[7];
    const float* bq       = (const float*)d_in[8];
    const float* Wk       = (const float*)d_in[9];
    const float* bk       = (const float*)d_in[10];
    const float* Wv       = (const float*)d_in[11];
    const float* bv       = (const float*)d_in[12];
    const float* Wo       = (const float*)d_in[13];
    const float* bo       = (const float*)d_in[14];
    const float* syn_w    = (const float*)d_in[15];
    const float* syn_b    = (const float*)d_in[16];
    const float* ln_syn_g = (const float*)d_in[17];
    const float* ln_syn_b = (const float*)d_in[18];
    const float* nlm_w1   = (const float*)d_in[19];
    const float* nlm_b1   = (const float*)d_in[20];
    const float* nlm_w2   = (const float*)d_in[21];
    const float* nlm_b2   = (const float*)d_in[22];
    const float* out_w    = (const float*)d_in[23];
    const float* out_b    = (const float*)d_in[24];
    const float* dec_a    = (const float*)d_in[25];
    const float* dec_o    = (const float*)d_in[26];
    const float* start_tr = (const float*)d_in[27];
    const float* start_ac = (const float*)d_in[28];
    const int*   idx_la   = (const int*)d_in[29];
    const int*   idx_ra   = (const int*)d_in[30];
    const int*   idx_lo   = (const int*)d_in[31];
    const int*   idx_ro   = (const int*)d_in[32];
    float* out = (float*)d_out;

    // workspace carve: barrier (256B) then floats
    unsigned* bar = (unsigned*)d_ws;
    float* w = (float*)d_ws + 64;
    float* kvbuf = w;            w += (size_t)8192 * 512;     // 4.19M
    float* khT   = w;            w += (size_t)8192 * 512;
    float* vhb   = w;            w += (size_t)8192 * 512;
    float* Wqq   = w;            w += (size_t)512 * 512;
    float* bqq   = w;            w += 512;
    float* W2    = w;            w += (size_t)512 * 4096;
    float* bias2 = w;            w += 4096;
    float* r_a   = w;            w += 512;
    float* r_o   = w;            w += 512;
    float* a_a   = w;            w += 2 * BB * NSA;           // ping-pong
    float* b_a   = w;            w += 2 * BB * NSA;
    float* a_o   = w;            w += 2 * BB * NSO;
    float* b_o   = w;            w += 2 * BB * NSO;
    float* act   = w;            w += BB * DD;
    float* trace = w;            w += (size_t)BB * MM * DD;   // 1.64M
    float* obuf  = w;            w += BB * DIN;
    float* upart = w;            w += (size_t)16 * 32 * 4096; // 2.1M
    float* ppart = w;            w += (size_t)8 * 32 * 1000;

    // ---- precompute ----
    init_kernel<<<6400, 256, 0, stream>>>(dec_a, dec_o, start_ac, start_tr, idx_lo, idx_ro,
                                          bar, r_a, r_o, a_a, b_a, a_o, b_o, act, trace);
    gemm64<1, 0><<<dim3(128, 8), 256, 0, stream>>>(x, kv_w, kv_b, kvbuf, 8192, 512, 512);
    ln_rows<<<8192, 256, 0, stream>>>(kvbuf, ln_kv_g, ln_kv_b);
    gemm64<0, 1><<<dim3(128, 8), 256, 0, stream>>>(kvbuf, Wk, bk, khT, 8192, 512, 512);
    gemm64<0, 2><<<dim3(128, 8), 256, 0, stream>>>(kvbuf, Wv, bv, vhb, 8192, 512, 512);
    gemm64<0, 0><<<dim3(8, 8), 256, 0, stream>>>(q_w, Wq, nullptr, Wqq, 512, 512, 512);
    bqq_kernel<<<2, 256, 0, stream>>>(q_b, Wq, bq, bqq);
    gemm64<0, 0><<<dim3(8, 64), 256, 0, stream>>>(Wo, syn_w, nullptr, W2, 512, 4096, 512);
    bias2_kernel<<<16, 256, 0, stream>>>(bo, syn_w, syn_b, bias2);

    float* out_sync = out + (size_t)BB * NOUT * TT + (size_t)BB * 2 * TT;

    // ---- the whole 50-tick recurrence: one persistent kernel ----
    TickArgs ta;
    ta.Wqq = Wqq; ta.bqq = bqq;
    ta.khT = khT; ta.vh = vhb;
    ta.W2 = W2; ta.syn_w = syn_w; ta.bias2 = bias2;
    ta.g_syn = ln_syn_g; ta.bt_syn = ln_syn_b;
    ta.w1 = nlm_w1; ta.b1 = nlm_b1; ta.w2 = nlm_w2; ta.b2 = nlm_b2;
    ta.out_w = out_w; ta.out_b = out_b;
    ta.r_a = r_a; ta.r_o = r_o;
    ta.la = idx_la; ta.ra = idx_ra; ta.lo = idx_lo; ta.ro = idx_ro;
    ta.a_a = a_a; ta.b_a = b_a; ta.a_o = a_o; ta.b_o = b_o;
    ta.act = act; ta.trace = trace; ta.obuf = obuf; ta.upart = upart; ta.ppart = ppart;
    ta.out = out; ta.out_sync = out_sync;
    ta.bar = bar;

    tick_kernel<<<NBLK, 256, 0, stream>>>(ta);
}

// Round 3
// 18251.755 us; speedup vs baseline: 3.1791x; 3.1791x over previous
//
#include <hip/hip_runtime.h>
#include <math.h>

// Problem constants
#define BB 32
#define CC 512
#define SS 256      // kv tokens
#define DD 2048     // d_model
#define DIN 512
#define NH 8
#define DHD 64
#define TT 50
#define MM 25
#define HHID 16
#define NSA 512
#define NSO 512
#define NOUT 1000

#define NBLK 256    // persistent grid size (== CU count; must all be resident)
#define BLKT 512    // threads per block (8 waves/CU for latency hiding)

// ---------------------------------------------------------------------------
// Coherent (cross-XCD) access helpers. RELAXED+AGENT compiles to sc0/sc1
// loads/stores that bypass the non-coherent per-XCD L2 and complete at the
// coherence point (MALL). This lets the grid barrier avoid ANY cache
// flush/invalidate, so weights stay L2-cached across all 250 barriers.
// ---------------------------------------------------------------------------
__device__ __forceinline__ float cld(const float* p) {
    return __hip_atomic_load(p, __ATOMIC_RELAXED, __HIP_MEMORY_SCOPE_AGENT);
}
__device__ __forceinline__ void cst(float* p, float v) {
    __hip_atomic_store(p, v, __ATOMIC_RELAXED, __HIP_MEMORY_SCOPE_AGENT);
}

// ---------------------------------------------------------------------------
// Init: barrier counter, decays, sync states (buffer 0 of ping-pong), act0,
// trace0
// ---------------------------------------------------------------------------
__global__ void init_kernel(const float* __restrict__ dec_a, const float* __restrict__ dec_o,
                            const float* __restrict__ start_act, const float* __restrict__ start_trace,
                            const int* __restrict__ idx_lo, const int* __restrict__ idx_ro,
                            unsigned* __restrict__ bar,
                            float* __restrict__ r_a, float* __restrict__ r_o,
                            float* __restrict__ a_a, float* __restrict__ b_a,
                            float* __restrict__ a_o, float* __restrict__ b_o,
                            float* __restrict__ act, float* __restrict__ trace)
{
    int i = blockIdx.x * 256 + threadIdx.x;
    if (i < 16) bar[i] = 0u;
    if (i < 512) {
        r_a[i] = expf(-fminf(fmaxf(dec_a[i], 0.f), 15.f));
        r_o[i] = expf(-fminf(fmaxf(dec_o[i], 0.f), 15.f));
    }
    if (i < BB * NSA) {
        a_a[i] = 0.f; b_a[i] = 0.f;
        int j = i & 511;
        a_o[i] = start_act[idx_lo[j]] * start_act[idx_ro[j]];
        b_o[i] = 1.f;
    }
    if (i < BB * DD) act[i] = start_act[i & (DD - 1)];
    if (i < BB * MM * DD) {
        int rem = i % (MM * DD);
        int m = rem / DD, d = rem % DD;
        trace[i] = start_trace[d * MM + m];   // start_trace is (D,M)
    }
}

// ---------------------------------------------------------------------------
// Generic 64x64 tiled GEMM (precompute only). AMODE 0: row-major A[row*K+k].
// AMODE 1: A is x (B,C,S) with row=(b,s), k=c. SMODE 0: plain row-major +
// bias. SMODE 1: store khT (B,H,DH,S). SMODE 2: store vh (B,H,S,DH).
// ---------------------------------------------------------------------------
template<int AMODE, int SMODE>
__global__ void gemm64(const float* __restrict__ A, const float* __restrict__ Bm,
                       const float* __restrict__ bias, float* __restrict__ Cm,
                       int Mdim, int Ndim, int Kdim)
{
    __shared__ float As[16 * 65];
    __shared__ float Bs[16 * 64];
    int row0 = blockIdx.x * 64;
    int col0 = blockIdx.y * 64;
    int t = threadIdx.x;
    int tx = t & 15, ty = t >> 4;
    float acc[4][4] = {};
    for (int k0 = 0; k0 < Kdim; k0 += 16) {
        if (AMODE == 0) {
            for (int i = t; i < 1024; i += 256) {
                int kk = i & 15, r = i >> 4;
                As[kk * 65 + r] = A[(size_t)(row0 + r) * Kdim + k0 + kk];
            }
        } else {
            int b = row0 / SS, s0 = row0 % SS;
            for (int i = t; i < 1024; i += 256) {
                int r = i & 63, kk = i >> 6;
                As[kk * 65 + r] = A[((size_t)b * CC + k0 + kk) * SS + s0 + r];
            }
        }
        for (int i = t; i < 1024; i += 256) {
            int c = i & 63, kk = i >> 6;
            Bs[kk * 64 + c] = Bm[(size_t)(k0 + kk) * Ndim + col0 + c];
        }
        __syncthreads();
        #pragma unroll
        for (int kk = 0; kk < 16; ++kk) {
            float a[4], bb[4];
            #pragma unroll
            for (int i = 0; i < 4; i++) a[i] = As[kk * 65 + ty * 4 + i];
            #pragma unroll
            for (int j = 0; j < 4; j++) bb[j] = Bs[kk * 64 + tx * 4 + j];
            #pragma unroll
            for (int i = 0; i < 4; i++)
                #pragma unroll
                for (int j = 0; j < 4; j++) acc[i][j] += a[i] * bb[j];
        }
        __syncthreads();
    }
    #pragma unroll
    for (int i = 0; i < 4; i++)
        #pragma unroll
        for (int j = 0; j < 4; j++) {
            int row = row0 + ty * 4 + i, col = col0 + tx * 4 + j;
            float v = acc[i][j] + (bias ? bias[col] : 0.f);
            if (SMODE == 0) {
                Cm[(size_t)row * Ndim + col] = v;
            } else if (SMODE == 1) {
                int b = row / SS, s = row % SS, h = col >> 6, dh = col & 63;
                Cm[(((size_t)b * NH + h) * DHD + dh) * SS + s] = v;
            } else {
                int b = row / SS, s = row % SS, h = col >> 6, dh = col & 63;
                Cm[(((size_t)b * NH + h) * SS + s) * DHD + dh] = v;
            }
        }
}

// LayerNorm over rows of 512 (in place), g/b applied
__global__ void ln_rows(float* __restrict__ buf, const float* __restrict__ g,
                        const float* __restrict__ bta)
{
    int row = blockIdx.x, t = threadIdx.x;
    __shared__ float red[256];
    float v0 = buf[(size_t)row * 512 + t];
    float v1 = buf[(size_t)row * 512 + 256 + t];
    red[t] = v0 + v1; __syncthreads();
    for (int off = 128; off; off >>= 1) { if (t < off) red[t] += red[t + off]; __syncthreads(); }
    float mu = red[0] * (1.f / 512.f); __syncthreads();
    float d0 = v0 - mu, d1 = v1 - mu;
    red[t] = d0 * d0 + d1 * d1; __syncthreads();
    for (int off = 128; off; off >>= 1) { if (t < off) red[t] += red[t + off]; __syncthreads(); }
    float rstd = 1.f / sqrtf(red[0] * (1.f / 512.f) + 1e-5f);
    buf[(size_t)row * 512 + t]       = d0 * rstd * g[t] + bta[t];
    buf[(size_t)row * 512 + 256 + t] = d1 * rstd * g[t + 256] + bta[t + 256];
}

// bqq = q_b @ Wq + bq
__global__ void bqq_kernel(const float* __restrict__ q_b, const float* __restrict__ Wq,
                           const float* __restrict__ bq, float* __restrict__ bqq)
{
    int c = blockIdx.x * 256 + threadIdx.x;
    if (c >= 512) return;
    float acc = bq[c];
    for (int k = 0; k < 512; k++) acc += q_b[k] * Wq[k * 512 + c];
    bqq[c] = acc;
}

// bias2 = bo @ syn_w[0:512,:] + syn_b
__global__ void bias2_kernel(const float* __restrict__ bo, const float* __restrict__ syn_w,
                             const float* __restrict__ syn_b, float* __restrict__ bias2)
{
    int c = blockIdx.x * 256 + threadIdx.x;
    if (c >= 4096) return;
    float acc = syn_b[c];
    for (int k = 0; k < 512; k++) acc += bo[k] * syn_w[(size_t)k * 4096 + c];
    bias2[c] = acc;
}

// ---------------------------------------------------------------------------
// Fence-free grid barrier. All cross-block data moves via cld/cst (sc1,
// write-through to MALL), so the barrier needs NO L2 writeback/invalidate.
// __threadfence_block() = per-wave s_waitcnt vmcnt(0) -> all this block's
// coherent stores have reached the MALL before the arrival add.
// Monotone counter: barrier k complete when ctr >= NBLK*k (no reset/ABA).
// ---------------------------------------------------------------------------
__device__ __forceinline__ void gsync(unsigned* __restrict__ ctr, unsigned target)
{
    __threadfence_block();     // drain this wave's stores (vmcnt(0)), no cache ops
    __syncthreads();           // all 8 waves drained
    if (threadIdx.x == 0) {
        __hip_atomic_fetch_add(ctr, 1u, __ATOMIC_RELAXED, __HIP_MEMORY_SCOPE_AGENT);
        while (__hip_atomic_load(ctr, __ATOMIC_RELAXED, __HIP_MEMORY_SCOPE_AGENT) < target)
            __builtin_amdgcn_s_sleep(8);
        asm volatile("" ::: "memory");
    }
    __syncthreads();
}

// ---------------------------------------------------------------------------
// Persistent tick kernel: the whole T=50 recurrence, 5 grid barriers/tick.
// Grid MUST be NBLK=256 blocks x BLKT=512 threads (1 block/CU, 8 waves/CU).
// ---------------------------------------------------------------------------
struct TickArgs {
    const float* Wqq; const float* bqq;
    const float* khT; const float* vh;
    const float* W2;  const float* syn_w; const float* bias2;
    const float* g_syn; const float* bt_syn;
    const float* w1; const float* b1; const float* w2; const float* b2;
    const float* out_w; const float* out_b;
    const float* r_a; const float* r_o;
    const int* la; const int* ra; const int* lo; const int* ro;
    float* a_a; float* b_a;      // [2][BB*512] ping-pong
    float* a_o; float* b_o;      // [2][BB*512] ping-pong
    float* act; float* trace; float* obuf; float* upart; float* ppart;
    float* out; float* out_sync;
    unsigned* bar;
};

// cert for one batch row, 512 threads. red = 512-float LDS scratch.
__device__ __forceinline__ void block_cert(const float* __restrict__ ppart,
                                           const float* __restrict__ out_b,
                                           float* __restrict__ d_out, int b, int t_iter,
                                           float* red)
{
    int t = threadIdx.x;
    float pv[2];
    float mx = -1e30f;
    #pragma unroll
    for (int ii = 0; ii < 2; ++ii) {
        int c = t + ii * 512;
        float v = -1e30f;
        if (c < 1000) {
            v = out_b[c];
            for (int ks = 0; ks < 8; ++ks) v += cld(&ppart[(size_t)(ks * 32 + b) * 1000 + c]);
            d_out[(size_t)b * NOUT * TT + (size_t)c * TT + t_iter] = v;
        }
        pv[ii] = v;
        mx = fmaxf(mx, v);
    }
    red[t] = mx; __syncthreads();
    for (int off = 256; off; off >>= 1) { if (t < off) red[t] = fmaxf(red[t], red[t + off]); __syncthreads(); }
    mx = red[0]; __syncthreads();
    float s1 = 0.f, s2 = 0.f;
    #pragma unroll
    for (int ii = 0; ii < 2; ++ii) {
        int c = t + ii * 512;
        if (c < 1000) { float xx = pv[ii] - mx; float e = expf(xx); s1 += e; s2 += e * xx; }
    }
    red[t] = s1; __syncthreads();
    for (int off = 256; off; off >>= 1) { if (t < off) red[t] += red[t + off]; __syncthreads(); }
    s1 = red[0]; __syncthreads();
    red[t] = s2; __syncthreads();
    for (int off = 256; off; off >>= 1) { if (t < off) red[t] += red[t + off]; __syncthreads(); }
    s2 = red[0];
    if (t == 0) {
        float ne = -(s2 / s1 - logf(s1)) * (1.f / logf(1000.f));
        size_t base = (size_t)BB * NOUT * TT + (size_t)b * 2 * TT + t_iter;
        d_out[base] = ne;
        d_out[base + TT] = 1.f - ne;
    }
    __syncthreads();   // red reused by next phase (P1 of next tick)
}

__global__ __launch_bounds__(BLKT) void tick_kernel(TickArgs A)
{
    __shared__ float smem[32 * 161];   // 20.6 KB, unioned across phases
    const int blk = blockIdx.x;
    const int tid = threadIdx.x;
    unsigned nb = 0;                   // barrier target accumulator

    for (int t = 0; t < TT; ++t) {
        const int par = t & 1;

        // ============ P1: sync_a + qh slice + attention, block = (b,h) ======
        {
            int b = blk >> 3, h = blk & 7;
            float* sa  = smem;           // 512
            float* qp  = smem + 512;     // 512
            float* qs  = smem + 1024;    // 64
            float* ps  = smem + 1088;    // 256
            float* red = smem + 1344;    // 512
            const float* aold = A.a_a + par * (BB * 512);
            const float* bold = A.b_a + par * (BB * 512);
            float* anew = A.a_a + (par ^ 1) * (BB * 512);
            float* bnew = A.b_a + (par ^ 1) * (BB * 512);
            const float* actb = A.act + b * DD;
            {
                int j = tid;   // 512 threads, one j each
                float p = cld(&actb[A.la[j]]) * cld(&actb[A.ra[j]]);
                float r = A.r_a[j];
                float aa = r * cld(&aold[b * 512 + j]) + p;
                float bb = r * cld(&bold[b * 512 + j]) + 1.f;
                sa[j] = aa / sqrtf(bb);
                if (h == 0) { cst(&anew[b * 512 + j], aa); cst(&bnew[b * 512 + j], bb); }
            }
            __syncthreads();
            // qh slice for this head: c = h*64 + cl, K split into 8 chunks
            {
                int cl = tid & 63, q = tid >> 6;
                const float* wcol = A.Wqq + h * 64 + cl;
                float acc = 0.f;
                #pragma unroll 8
                for (int k = q * 64; k < q * 64 + 64; ++k)
                    acc += sa[k] * wcol[k * 512];
                qp[tid] = acc;
            }
            __syncthreads();
            if (tid < 64) {
                float s = A.bqq[h * 64 + tid];
                #pragma unroll
                for (int i = 0; i < 8; ++i) s += qp[tid + 64 * i];
                qs[tid] = s;
            }
            __syncthreads();
            // scores (threads 0..255 = s)
            const float* kb = A.khT + (size_t)blk * 64 * 256;   // [dh][s]
            float sc = 0.f;
            if (tid < 256) {
                #pragma unroll 8
                for (int dh = 0; dh < 64; ++dh) sc += qs[dh] * kb[dh * 256 + tid];
                sc *= 0.125f;
            }
            red[tid] = (tid < 256) ? sc : -1e30f;
            __syncthreads();
            for (int off = 256; off; off >>= 1) { if (tid < off) red[tid] = fmaxf(red[tid], red[tid + off]); __syncthreads(); }
            float mx = red[0]; __syncthreads();
            float e = (tid < 256) ? expf(sc - mx) : 0.f;
            red[tid] = e; __syncthreads();
            for (int off = 256; off; off >>= 1) { if (tid < off) red[tid] += red[tid + off]; __syncthreads(); }
            float inv = 1.f / red[0];
            if (tid < 256) ps[tid] = e * inv;
            __syncthreads();
            // PV: dh x 8 chunks of 32 s
            {
                int dh = tid & 63, ch = tid >> 6;
                const float* vb = A.vh + (size_t)blk * 256 * 64;    // [s][dh]
                float acc = 0.f;
                for (int s = ch * 32; s < ch * 32 + 32; ++s) acc += ps[s] * vb[s * 64 + dh];
                red[tid] = acc; __syncthreads();
                if (tid < 256) red[tid] += red[tid + 256]; __syncthreads();
                if (tid < 128) red[tid] += red[tid + 128]; __syncthreads();
                if (tid < 64) cst(&A.obuf[b * 512 + h * 64 + tid], red[tid] + red[tid + 64]);
            }
        }
        nb += NBLK; gsync(A.bar, nb);

        // ============ P2: synapse GEMM, 512 k-split units, 2 per block ======
        for (int rep = 0; rep < 2; ++rep) {
            int unit = blk * 2 + rep;
            int n0 = (unit & 31) * 128;
            int ks = unit >> 5;
            int k0 = ks * 160;
            float* As = smem;   // 32*161
            __syncthreads();
            for (int i = tid; i < 32 * 160; i += BLKT) {   // 10 iters
                int k = i % 160, r = i / 160;
                int kk = k0 + k;
                float v = (kk < 512) ? cld(&A.obuf[r * 512 + kk])
                                     : cld(&A.act[r * 2048 + (kk - 512)]);
                As[r * 161 + k] = v;
            }
            __syncthreads();
            int ct = tid & 31, rt = tid >> 5;   // rt 0..15 -> 2 rows each
            int c0 = n0 + ct * 4;
            int r2 = rt * 2;
            float acc[2][4] = {};
            #pragma unroll 4
            for (int k = 0; k < 160; ++k) {
                int kk = k0 + k;
                const float* wr = (kk < 512 ? A.W2 : A.syn_w) + (size_t)kk * 4096 + c0;
                float4 w4 = *(const float4*)wr;
                float a0 = As[(r2 + 0) * 161 + k];
                float a1 = As[(r2 + 1) * 161 + k];
                acc[0][0] += a0 * w4.x; acc[0][1] += a0 * w4.y; acc[0][2] += a0 * w4.z; acc[0][3] += a0 * w4.w;
                acc[1][0] += a1 * w4.x; acc[1][1] += a1 * w4.y; acc[1][2] += a1 * w4.z; acc[1][3] += a1 * w4.w;
            }
            #pragma unroll
            for (int i = 0; i < 2; i++) {
                float* dst = A.upart + ((size_t)(ks * 32) + r2 + i) * 4096 + c0;
                cst(dst + 0, acc[i][0]); cst(dst + 1, acc[i][1]);
                cst(dst + 2, acc[i][2]); cst(dst + 3, acc[i][3]);
            }
        }
        nb += NBLK; gsync(A.bar, nb);

        // ============ P3: glu_ln (blk 0..31) ================================
        if (blk < 32) {
            int b = blk;
            float* red = smem;   // 512
            float vals[4];
            float loc = 0.f;
            #pragma unroll
            for (int ii = 0; ii < 4; ++ii) {
                int d = tid + ii * 512;
                float a = A.bias2[d], bb = A.bias2[d + 2048];
                for (int ks = 0; ks < 16; ++ks) {
                    const float* rowp = A.upart + (size_t)(ks * 32 + b) * 4096;
                    a += cld(&rowp[d]);
                    bb += cld(&rowp[d + 2048]);
                }
                float gl = a * (1.f / (1.f + expf(-bb)));
                vals[ii] = gl; loc += gl;
            }
            red[tid] = loc; __syncthreads();
            for (int off = 256; off; off >>= 1) { if (tid < off) red[tid] += red[tid + off]; __syncthreads(); }
            float mu = red[0] * (1.f / 2048.f); __syncthreads();
            float l2 = 0.f;
            #pragma unroll
            for (int ii = 0; ii < 4; ++ii) { float dq = vals[ii] - mu; l2 += dq * dq; }
            red[tid] = l2; __syncthreads();
            for (int off = 256; off; off >>= 1) { if (tid < off) red[tid] += red[tid + off]; __syncthreads(); }
            float rstd = 1.f / sqrtf(red[0] * (1.f / 2048.f) + 1e-5f);
            float* trow = A.trace + ((size_t)b * MM + (t % MM)) * DD;
            #pragma unroll
            for (int ii = 0; ii < 4; ++ii) {
                int d = tid + ii * 512;
                cst(&trow[d], (vals[ii] - mu) * rstd * A.g_syn[d] + A.bt_syn[d]);
            }
        }
        nb += NBLK; gsync(A.bar, nb);

        // ============ P4: per-neuron MLP -> act (blk 0..127) ================
        if (blk < 128) {
            int i = blk * BLKT + tid;
            int b = i >> 11, d = i & 2047;
            float hp[32];
            #pragma unroll
            for (int h = 0; h < 32; h++) hp[h] = A.b1[d * 32 + h];
            const float* tr = A.trace + (size_t)b * MM * DD;
            for (int m = 0; m < 25; m++) {
                int mph = (t + 1 + m) % 25;     // logical->physical circular map
                float tv = cld(&tr[mph * DD + d]);
                #pragma unroll
                for (int h = 0; h < 32; h++) hp[h] += tv * A.w1[((size_t)m * 32 + h) * DD + d];
            }
            float o0 = A.b2[d * 2], o1 = A.b2[d * 2 + 1];
            #pragma unroll
            for (int h = 0; h < 16; h++) {
                float hv = hp[h] * (1.f / (1.f + expf(-hp[h + 16])));
                o0 += hv * A.w2[((size_t)h * 2) * DD + d];
                o1 += hv * A.w2[((size_t)h * 2 + 1) * DD + d];
            }
            cst(&A.act[i], o0 * (1.f / (1.f + expf(-o1))));
        }
        nb += NBLK; gsync(A.bar, nb);

        // ============ P5: sync_o fused into pred GEMM (blk 0..63) ===========
        if (blk < 64) {
            int ks = blk >> 3, ctile = blk & 7;
            int k0 = ks * 64;
            const float* aold = A.a_o + par * (BB * 512);
            const float* bold = A.b_o + par * (BB * 512);
            float* anew = A.a_o + (par ^ 1) * (BB * 512);
            float* bnew = A.b_o + (par ^ 1) * (BB * 512);
            float* As = smem;   // 32*65
            #pragma unroll
            for (int q = 0; q < 4; ++q) {
                int idx = tid + q * 512;          // 0..2047
                int r = idx >> 6, jl = idx & 63;
                int j = k0 + jl;
                const float* actb = A.act + r * DD;
                float p = cld(&actb[A.lo[j]]) * cld(&actb[A.ro[j]]);
                float rr = A.r_o[j];
                float aa = rr * cld(&aold[r * 512 + j]) + p;
                float bb = rr * cld(&bold[r * 512 + j]) + 1.f;
                float s = aa / sqrtf(bb);
                As[r * 65 + jl] = s;
                if (ctile == 0) {
                    cst(&anew[r * 512 + j], aa);
                    cst(&bnew[r * 512 + j], bb);
                    if (t == TT - 1) A.out_sync[r * 512 + j] = s;
                }
            }
            __syncthreads();
            int ct = tid & 31, rt = tid >> 5;   // rt 0..15 -> 2 rows each
            int cc = ctile * 128 + ct * 4;
            int r2 = rt * 2;
            if (cc < 1000) {
                float acc[2][4] = {};
                #pragma unroll 4
                for (int k = 0; k < 64; ++k) {
                    const float* wr = A.out_w + (size_t)(k0 + k) * 1000 + cc;
                    float w0 = wr[0], w1 = wr[1], w2 = wr[2], w3 = wr[3];
                    float a0 = As[(r2 + 0) * 65 + k];
                    float a1 = As[(r2 + 1) * 65 + k];
                    acc[0][0] += a0 * w0; acc[0][1] += a0 * w1; acc[0][2] += a0 * w2; acc[0][3] += a0 * w3;
                    acc[1][0] += a1 * w0; acc[1][1] += a1 * w1; acc[1][2] += a1 * w2; acc[1][3] += a1 * w3;
                }
                #pragma unroll
                for (int i = 0; i < 2; i++)
                    #pragma unroll
                    for (int j = 0; j < 4; j++)
                        cst(&A.ppart[(size_t)(ks * 32 + r2 + i) * 1000 + cc + j], acc[i][j]);
            }
        }
        nb += NBLK; gsync(A.bar, nb);

        // ============ P6: cert for tick t (blk 224..255), no trailing sync ==
        // Overlaps next tick's P1. Its only input (ppart) is next written in
        // P5 of tick t+1, which is 4 barriers away -> race-free.
        if (blk >= 224) {
            block_cert(A.ppart, A.out_b, A.out, blk - 224, t, smem);
        }
    }
}

// ---------------------------------------------------------------------------
extern "C" void kernel_launch(void* const* d_in, const int* in_sizes, int n_in,
                              void* d_out, int out_size, void* d_ws, size_t ws_size,
                              hipStream_t stream)
{
    const float* x        = (const float*)d_in[0];
    const float* kv_w     = (const float*)d_in[1];
    const float* kv_b     = (const float*)d_in[2];
    const float* ln_kv_g  = (const float*)d_in[3];
    const float* ln_kv_b  = (const float*)d_in[4];
    const float* q_w      = (const float*)d_in[5];
    const float* q_b      = (const float*)d_in[6];
    const float* Wq       = (const float*)d_in[7];
    const float* bq       = (const float*)d_in[8];
    const float* Wk       = (const float*)d_in[9];
    const float* bk       = (const float*)d_in[10];
    const float* Wv       = (const float*)d_in[11];
    const float* bv       = (const float*)d_in[12];
    const float* Wo       = (const float*)d_in[13];
    const float* bo       = (const float*)d_in[14];
    const float* syn_w    = (const float*)d_in[15];
    const float* syn_b    = (const float*)d_in[16];
    const float* ln_syn_g = (const float*)d_in[17];
    const float* ln_syn_b = (const float*)d_in[18];
    const float* nlm_w1   = (const float*)d_in[19];
    const float* nlm_b1   = (const float*)d_in[20];
    const float* nlm_w2   = (const float*)d_in[21];
    const float* nlm_b2   = (const float*)d_in[22];
    const float* out_w    = (const float*)d_in[23];
    const float* out_b    = (const float*)d_in[24];
    const float* dec_a    = (const float*)d_in[25];
    const float* dec_o    = (const float*)d_in[26];
    const float* start_tr = (const float*)d_in[27];
    const float* start_ac = (const float*)d_in[28];
    const int*   idx_la   = (const int*)d_in[29];
    const int*   idx_ra   = (const int*)d_in[30];
    const int*   idx_lo   = (const int*)d_in[31];
    const int*   idx_ro   = (const int*)d_in[32];
    float* out = (float*)d_out;

    // workspace carve: barrier (256B) then floats
    unsigned* bar = (unsigned*)d_ws;
    float* w = (float*)d_ws + 64;
    float* kvbuf = w;            w += (size_t)8192 * 512;     // 4.19M
    float* khT   = w;            w += (size_t)8192 * 512;
    float* vhb   = w;            w += (size_t)8192 * 512;
    float* Wqq   = w;            w += (size_t)512 * 512;
    float* bqq   = w;            w += 512;
    float* W2    = w;            w += (size_t)512 * 4096;
    float* bias2 = w;            w += 4096;
    float* r_a   = w;            w += 512;
    float* r_o   = w;            w += 512;
    float* a_a   = w;            w += 2 * BB * NSA;           // ping-pong
    float* b_a   = w;            w += 2 * BB * NSA;
    float* a_o   = w;            w += 2 * BB * NSO;
    float* b_o   = w;            w += 2 * BB * NSO;
    float* act   = w;            w += BB * DD;
    float* trace = w;            w += (size_t)BB * MM * DD;   // 1.64M
    float* obuf  = w;            w += BB * DIN;
    float* upart = w;            w += (size_t)16 * 32 * 4096; // 2.1M
    float* ppart = w;            w += (size_t)8 * 32 * 1000;

    // ---- precompute ----
    init_kernel<<<6400, 256, 0, stream>>>(dec_a, dec_o, start_ac, start_tr, idx_lo, idx_ro,
                                          bar, r_a, r_o, a_a, b_a, a_o, b_o, act, trace);
    gemm64<1, 0><<<dim3(128, 8), 256, 0, stream>>>(x, kv_w, kv_b, kvbuf, 8192, 512, 512);
    ln_rows<<<8192, 256, 0, stream>>>(kvbuf, ln_kv_g, ln_kv_b);
    gemm64<0, 1><<<dim3(128, 8), 256, 0, stream>>>(kvbuf, Wk, bk, khT, 8192, 512, 512);
    gemm64<0, 2><<<dim3(128, 8), 256, 0, stream>>>(kvbuf, Wv, bv, vhb, 8192, 512, 512);
    gemm64<0, 0><<<dim3(8, 8), 256, 0, stream>>>(q_w, Wq, nullptr, Wqq, 512, 512, 512);
    bqq_kernel<<<2, 256, 0, stream>>>(q_b, Wq, bq, bqq);
    gemm64<0, 0><<<dim3(8, 64), 256, 0, stream>>>(Wo, syn_w, nullptr, W2, 512, 4096, 512);
    bias2_kernel<<<16, 256, 0, stream>>>(bo, syn_w, syn_b, bias2);

    float* out_sync = out + (size_t)BB * NOUT * TT + (size_t)BB * 2 * TT;

    // ---- the whole 50-tick recurrence: one persistent kernel ----
    TickArgs ta;
    ta.Wqq = Wqq; ta.bqq = bqq;
    ta.khT = khT; ta.vh = vhb;
    ta.W2 = W2; ta.syn_w = syn_w; ta.bias2 = bias2;
    ta.g_syn = ln_syn_g; ta.bt_syn = ln_syn_b;
    ta.w1 = nlm_w1; ta.b1 = nlm_b1; ta.w2 = nlm_w2; ta.b2 = nlm_b2;
    ta.out_w = out_w; ta.out_b = out_b;
    ta.r_a = r_a; ta.r_o = r_o;
    ta.la = idx_la; ta.ra = idx_ra; ta.lo = idx_lo; ta.ro = idx_ro;
    ta.a_a = a_a; ta.b_a = b_a; ta.a_o = a_o; ta.b_o = b_o;
    ta.act = act; ta.trace = trace; ta.obuf = obuf; ta.upart = upart; ta.ppart = ppart;
    ta.out = out; ta.out_sync = out_sync;
    ta.bar = bar;

    tick_kernel<<<NBLK, BLKT, 0, stream>>>(ta);
}